// Round 1
// baseline (986.497 us; speedup 1.0000x reference)
//
#include <hip/hip_runtime.h>
#include <math.h>

__device__ __forceinline__ float act_lrelu(float x) { return x >= 0.0f ? x : 0.01f * x; }
__device__ __forceinline__ float act_gelu(float x) { return 0.5f * x * (1.0f + erff(x * 0.7071067811865475f)); }
__device__ __forceinline__ float dot4(float4 a, float4 b) {
    return a.x * b.x + a.y * b.y + a.z * b.z + a.w * b.w;
}

// Generic fp32 GEMM: C = act(A @ B + bias)
//  A: [M][K] row-major, or (ATRANS) stored [K][M] (lda = M)
//  B: [K][N] row-major, or (BTRANS) stored [N][K] (i.e. X @ W^T with W=[N][K])
//  batch z: off = (z>>3)*s_outer + (z&7)*s_inner  (head split fixed at 8)
//  C index = m*cm + n*cn  (allows column-major / scatter epilogues)
//  ACT: 0=none 1=lrelu 2=gelu.  BIAS_M: bias indexed by m (else by n).
template <bool ATRANS, bool BTRANS, int ACT, bool BIAS_M>
__global__ __launch_bounds__(256) void gemm_f32(
    const float* __restrict__ A, const float* __restrict__ B,
    const float* __restrict__ bias, float* __restrict__ C,
    int M, int N, int K,
    long long sAo, long long sAi, long long sBo, long long sBi,
    long long sCo, long long sCi, int cm, int cn, int sbi)
{
    const int z = blockIdx.z;
    A += (long long)(z >> 3) * sAo + (long long)(z & 7) * sAi;
    B += (long long)(z >> 3) * sBo + (long long)(z & 7) * sBi;
    C += (long long)(z >> 3) * sCo + (long long)(z & 7) * sCi;

    __shared__ float As[16][68];
    __shared__ float Bs[16][68];

    const int m0 = blockIdx.y * 64;
    const int n0 = blockIdx.x * 64;
    const int tid = threadIdx.x;
    const int tx = tid & 15;
    const int ty = tid >> 4;

    float acc[4][4] = {};

    for (int k0 = 0; k0 < K; k0 += 16) {
        if constexpr (ATRANS) {
            const int mm = tid & 63, kb = tid >> 6;
            #pragma unroll
            for (int i = 0; i < 4; ++i) {
                const int kk = kb * 4 + i;
                As[kk][mm] = A[(long long)(k0 + kk) * M + (m0 + mm)];
            }
        } else {
            const int kk = tid & 15, mb = tid >> 4;
            #pragma unroll
            for (int i = 0; i < 4; ++i)
                As[kk][mb + i * 16] = A[(long long)(m0 + mb + i * 16) * K + (k0 + kk)];
        }
        if constexpr (BTRANS) {
            const int kk = tid & 15, nb = tid >> 4;
            #pragma unroll
            for (int i = 0; i < 4; ++i)
                Bs[kk][nb + i * 16] = B[(long long)(n0 + nb + i * 16) * K + (k0 + kk)];
        } else {
            const int nn = tid & 63, kb = tid >> 6;
            #pragma unroll
            for (int i = 0; i < 4; ++i) {
                const int kk = kb * 4 + i;
                Bs[kk][nn] = B[(long long)(k0 + kk) * N + (n0 + nn)];
            }
        }
        __syncthreads();
        #pragma unroll
        for (int kk = 0; kk < 16; ++kk) {
            const float4 a = *(const float4*)&As[kk][ty * 4];
            const float4 b = *(const float4*)&Bs[kk][tx * 4];
            acc[0][0] += a.x * b.x; acc[0][1] += a.x * b.y; acc[0][2] += a.x * b.z; acc[0][3] += a.x * b.w;
            acc[1][0] += a.y * b.x; acc[1][1] += a.y * b.y; acc[1][2] += a.y * b.z; acc[1][3] += a.y * b.w;
            acc[2][0] += a.z * b.x; acc[2][1] += a.z * b.y; acc[2][2] += a.z * b.z; acc[2][3] += a.z * b.w;
            acc[3][0] += a.w * b.x; acc[3][1] += a.w * b.y; acc[3][2] += a.w * b.z; acc[3][3] += a.w * b.w;
        }
        __syncthreads();
    }

    const float* bp = bias ? (bias + (long long)(z & 7) * sbi) : nullptr;
    #pragma unroll
    for (int i = 0; i < 4; ++i) {
        const int m = m0 + ty * 4 + i;
        #pragma unroll
        for (int j = 0; j < 4; ++j) {
            const int n = n0 + tx * 4 + j;
            float v = acc[i][j];
            if (bp) v += BIAS_M ? bp[m] : bp[n];
            if constexpr (ACT == 1) v = act_lrelu(v);
            if constexpr (ACT == 2) v = act_gelu(v);
            C[(long long)m * cm + (long long)n * cn] = v;
        }
    }
}

// fp32 flash attention: O = softmax(Q K^T * scale) V
// Q: [32][1024][128], K/V: [32][2048][128], O: [32][1024][128]
// grid (16 m-tiles, 32 bh), block 256. 64-query tile, 32-key chunks.
__global__ __launch_bounds__(256) void flash_attn_f32(
    const float* __restrict__ Q, const float* __restrict__ Kx,
    const float* __restrict__ V, float* __restrict__ O)
{
    const int bh = blockIdx.y;
    const int m0 = blockIdx.x * 64;
    const int tid = threadIdx.x;
    const int tx = tid & 15;
    const int ty = tid >> 4;

    __shared__ float qs[64][132];
    __shared__ float ks[32][132];
    __shared__ float vs[32][132];
    __shared__ float Ps[64][33];
    __shared__ float mrow[64], lrow[64], frow[64];

    const float* Qb = Q + (long long)bh * 1024 * 128;
    const float* Kb = Kx + (long long)bh * 2048 * 128;
    const float* Vb = V + (long long)bh * 2048 * 128;

    for (int idx = tid; idx < 64 * 32; idx += 256) {
        const int r = idx >> 5, c4 = (idx & 31) * 4;
        *(float4*)&qs[r][c4] = *(const float4*)&Qb[(long long)(m0 + r) * 128 + c4];
    }
    if (tid < 64) { mrow[tid] = -1e30f; lrow[tid] = 0.0f; }

    float o[4][8] = {};

    for (int nt = 0; nt < 64; ++nt) {
        const int n0 = nt * 32;
        __syncthreads();  // prev PV done reading ks/vs/Ps; first iter: qs/stats visible after next barrier
        for (int idx = tid; idx < 32 * 32; idx += 256) {
            const int r = idx >> 5, c4 = (idx & 31) * 4;
            *(float4*)&ks[r][c4] = *(const float4*)&Kb[(long long)(n0 + r) * 128 + c4];
            *(float4*)&vs[r][c4] = *(const float4*)&Vb[(long long)(n0 + r) * 128 + c4];
        }
        __syncthreads();

        // S tile: rows ty*4+{0..3}, cols tx*2+{0,1}
        float s[4][2] = {};
        #pragma unroll 8
        for (int kk = 0; kk < 128; kk += 4) {
            float4 a[4], b[2];
            #pragma unroll
            for (int i = 0; i < 4; ++i) a[i] = *(const float4*)&qs[ty * 4 + i][kk];
            #pragma unroll
            for (int j = 0; j < 2; ++j) b[j] = *(const float4*)&ks[tx * 2 + j][kk];
            #pragma unroll
            for (int i = 0; i < 4; ++i)
                #pragma unroll
                for (int j = 0; j < 2; ++j) s[i][j] += dot4(a[i], b[j]);
        }
        #pragma unroll
        for (int i = 0; i < 4; ++i)
            #pragma unroll
            for (int j = 0; j < 2; ++j)
                Ps[ty * 4 + i][tx * 2 + j] = s[i][j] * 0.08838834764831845f;
        __syncthreads();

        // online softmax stats: 4 threads per row
        {
            const int row = tid >> 2, part = tid & 3;
            float mx = -1e30f;
            #pragma unroll
            for (int c = 0; c < 8; ++c) mx = fmaxf(mx, Ps[row][part * 8 + c]);
            mx = fmaxf(mx, __shfl_xor(mx, 1, 64));
            mx = fmaxf(mx, __shfl_xor(mx, 2, 64));
            const float oldm = mrow[row];
            const float newm = fmaxf(oldm, mx);
            float sum = 0.0f;
            #pragma unroll
            for (int c = 0; c < 8; ++c) {
                const float e = __expf(Ps[row][part * 8 + c] - newm);
                Ps[row][part * 8 + c] = e;
                sum += e;
            }
            sum += __shfl_xor(sum, 1, 64);
            sum += __shfl_xor(sum, 2, 64);
            if (part == 0) {
                frow[row] = __expf(oldm - newm);
                lrow[row] = lrow[row] * frow[row] + sum;
                mrow[row] = newm;
            }
        }
        __syncthreads();

        // rescale O, accumulate PV: rows ty*4+{0..3}, d cols tx*8+{0..7}
        {
            float f[4];
            #pragma unroll
            for (int i = 0; i < 4; ++i) f[i] = frow[ty * 4 + i];
            #pragma unroll
            for (int i = 0; i < 4; ++i)
                #pragma unroll
                for (int j = 0; j < 8; ++j) o[i][j] *= f[i];
            #pragma unroll 4
            for (int n = 0; n < 32; ++n) {
                float p[4];
                #pragma unroll
                for (int i = 0; i < 4; ++i) p[i] = Ps[ty * 4 + i][n];
                const float4 va = *(const float4*)&vs[n][tx * 8];
                const float4 vb = *(const float4*)&vs[n][tx * 8 + 4];
                #pragma unroll
                for (int i = 0; i < 4; ++i) {
                    o[i][0] += p[i] * va.x; o[i][1] += p[i] * va.y;
                    o[i][2] += p[i] * va.z; o[i][3] += p[i] * va.w;
                    o[i][4] += p[i] * vb.x; o[i][5] += p[i] * vb.y;
                    o[i][6] += p[i] * vb.z; o[i][7] += p[i] * vb.w;
                }
            }
        }
    }

    float* Ob = O + (long long)bh * 1024 * 128;
    #pragma unroll
    for (int i = 0; i < 4; ++i) {
        const float inv = 1.0f / lrow[ty * 4 + i];
        const int m = m0 + ty * 4 + i;
        #pragma unroll
        for (int j = 0; j < 8; ++j)
            Ob[(long long)m * 128 + tx * 8 + j] = o[i][j] * inv;
    }
}

extern "C" void kernel_launch(void* const* d_in, const int* in_sizes, int n_in,
                              void* d_out, int out_size, void* d_ws, size_t ws_size,
                              hipStream_t stream)
{
    (void)in_sizes; (void)n_in; (void)out_size; (void)ws_size;
    const float* query = (const float*)d_in[0];
    const float* fts   = (const float*)d_in[1];
    const float* wqc = (const float*)d_in[2];
    const float* bqc = (const float*)d_in[3];
    const float* wq1 = (const float*)d_in[4];
    const float* bq1 = (const float*)d_in[5];
    const float* wq2 = (const float*)d_in[6];
    const float* bq2 = (const float*)d_in[7];
    const float* wk1 = (const float*)d_in[8];
    const float* bk1 = (const float*)d_in[9];
    const float* wk2 = (const float*)d_in[10];
    const float* bk2 = (const float*)d_in[11];
    const float* wv1 = (const float*)d_in[12];
    const float* bv1 = (const float*)d_in[13];
    const float* wv2 = (const float*)d_in[14];
    const float* bv2 = (const float*)d_in[15];
    const float* wo  = (const float*)d_in[16];
    const float* bo  = (const float*)d_in[17];
    const float* wf1 = (const float*)d_in[18];
    const float* bf1 = (const float*)d_in[19];
    const float* wf2 = (const float*)d_in[20];
    const float* bf2 = (const float*)d_in[21];
    float* out = (float*)d_out;

    // ws layout (128 MB total), with lifetime-safe aliasing:
    char* ws = (char*)d_ws;
    float* kbuf = (float*)(ws + 0LL);           // 32 MB  [32][2048][128]
    float* vbuf = (float*)(ws + 33554432LL);    // 32 MB  [32][2048][128]
    float* tbuf = (float*)(ws + 67108864LL);    // 32 MB  temp / later x [4][1024][1024]
    float* qh   = (float*)(ws + 100663296LL);   // 16 MB  [32][1024][128], later enh
    float* qbuf = (float*)(ws + 117440512LL);   // 16 MB  [32][1024][128], later y
    float* enh  = qh;
    float* xbuf = tbuf;
    float* ybuf = qbuf;

    // 1. q-conv: per (b,head): C[o=128][hw=1024] = wqc_head @ query_b, scatter to qh[bh][hw][o]
    gemm_f32<false, false, 0, true><<<dim3(16, 2, 32), 256, 0, stream>>>(
        wqc, query, bqc, qh, 128, 1024, 128,
        0LL, 16384LL, 131072LL, 0LL, 1048576LL, 131072LL, 1, 128, 128);
    // 2. t = lrelu(qh @ wq1^T + bq1)   rows 32768
    gemm_f32<false, true, 1, false><<<dim3(2, 512, 1), 256, 0, stream>>>(
        qh, wq1, bq1, tbuf, 32768, 128, 128, 0, 0, 0, 0, 0, 0, 128, 1, 0);
    // 3. q = gelu(t @ wq2^T + bq2)
    gemm_f32<false, true, 2, false><<<dim3(2, 512, 1), 256, 0, stream>>>(
        tbuf, wq2, bq2, qbuf, 32768, 128, 128, 0, 0, 0, 0, 0, 0, 128, 1, 0);
    // 4. t = lrelu(ft @ wk1^T + bk1)   ft[n][c] = fts[bh][c][n]  (ATRANS)
    gemm_f32<true, true, 1, false><<<dim3(2, 32, 32), 256, 0, stream>>>(
        fts, wk1, bk1, tbuf, 2048, 128, 128,
        2097152LL, 262144LL, 0, 0, 2097152LL, 262144LL, 128, 1, 0);
    // 5. k = gelu(t @ wk2^T + bk2)     rows 65536
    gemm_f32<false, true, 2, false><<<dim3(2, 1024, 1), 256, 0, stream>>>(
        tbuf, wk2, bk2, kbuf, 65536, 128, 128, 0, 0, 0, 0, 0, 0, 128, 1, 0);
    // 6. t = lrelu(ft @ wv1^T + bv1)
    gemm_f32<true, true, 1, false><<<dim3(2, 32, 32), 256, 0, stream>>>(
        fts, wv1, bv1, tbuf, 2048, 128, 128,
        2097152LL, 262144LL, 0, 0, 2097152LL, 262144LL, 128, 1, 0);
    // 7. v = gelu(t @ wv2^T + bv2)
    gemm_f32<false, true, 2, false><<<dim3(2, 1024, 1), 256, 0, stream>>>(
        tbuf, wv2, bv2, vbuf, 65536, 128, 128, 0, 0, 0, 0, 0, 0, 128, 1, 0);
    // 8. enh = softmax(q k^T * scale) v
    flash_attn_f32<<<dim3(16, 32), 256, 0, stream>>>(qbuf, kbuf, vbuf, enh);
    // 9. x[b][hw][head*128+o] = enh[bh] @ wo^T + bo
    gemm_f32<false, true, 0, false><<<dim3(2, 16, 32), 256, 0, stream>>>(
        enh, wo, bo, xbuf, 1024, 128, 128,
        1048576LL, 131072LL, 0, 0, 1048576LL, 128LL, 1024, 1, 0);
    // 10. y = lrelu(x @ wf1^T + bf1)   [4096][1024] @ [128][1024]^T
    gemm_f32<false, true, 1, false><<<dim3(2, 64, 1), 256, 0, stream>>>(
        xbuf, wf1, bf1, ybuf, 4096, 128, 1024, 0, 0, 0, 0, 0, 0, 128, 1, 0);
    // 11. out = lrelu(y @ wf2^T + bf2)
    gemm_f32<false, true, 1, false><<<dim3(2, 64, 1), 256, 0, stream>>>(
        ybuf, wf2, bf2, out, 4096, 128, 128, 0, 0, 0, 0, 0, 0, 128, 1, 0);
}

// Round 2
// 459.395 us; speedup vs baseline: 2.1474x; 2.1474x over previous
//
#include <hip/hip_runtime.h>
#include <math.h>

typedef __attribute__((ext_vector_type(8))) __bf16 bf16x8;
typedef __attribute__((ext_vector_type(4))) float f32x4;

__device__ __forceinline__ float act_lrelu(float x) { return x >= 0.0f ? x : 0.01f * x; }
__device__ __forceinline__ float act_gelu(float x) { return 0.5f * x * (1.0f + erff(x * 0.7071067811865475f)); }
__device__ __forceinline__ float dot4(float4 a, float4 b) {
    return a.x * b.x + a.y * b.y + a.z * b.z + a.w * b.w;
}
__device__ __forceinline__ ushort f2bf(float f) {
    unsigned u = __builtin_bit_cast(unsigned, f);
    u += 0x7fffu + ((u >> 16) & 1u);   // RTNE
    return (ushort)(u >> 16);
}

// Generic fp32 GEMM: C = act(A @ B + bias), output type CT (float or ushort=bf16)
template <bool ATRANS, bool BTRANS, int ACT, bool BIAS_M, typename CT>
__global__ __launch_bounds__(256) void gemm_f32(
    const float* __restrict__ A, const float* __restrict__ B,
    const float* __restrict__ bias, CT* __restrict__ C,
    int M, int N, int K,
    long long sAo, long long sAi, long long sBo, long long sBi,
    long long sCo, long long sCi, int cm, int cn, int sbi)
{
    const int z = blockIdx.z;
    A += (long long)(z >> 3) * sAo + (long long)(z & 7) * sAi;
    B += (long long)(z >> 3) * sBo + (long long)(z & 7) * sBi;
    C += (long long)(z >> 3) * sCo + (long long)(z & 7) * sCi;

    __shared__ float As[16][68];
    __shared__ float Bs[16][68];

    const int m0 = blockIdx.y * 64;
    const int n0 = blockIdx.x * 64;
    const int tid = threadIdx.x;
    const int tx = tid & 15;
    const int ty = tid >> 4;

    float acc[4][4] = {};

    for (int k0 = 0; k0 < K; k0 += 16) {
        if constexpr (ATRANS) {
            const int mm = tid & 63, kb = tid >> 6;
            #pragma unroll
            for (int i = 0; i < 4; ++i) {
                const int kk = kb * 4 + i;
                As[kk][mm] = A[(long long)(k0 + kk) * M + (m0 + mm)];
            }
        } else {
            const int kk = tid & 15, mb = tid >> 4;
            #pragma unroll
            for (int i = 0; i < 4; ++i)
                As[kk][mb + i * 16] = A[(long long)(m0 + mb + i * 16) * K + (k0 + kk)];
        }
        if constexpr (BTRANS) {
            const int kk = tid & 15, nb = tid >> 4;
            #pragma unroll
            for (int i = 0; i < 4; ++i)
                Bs[kk][nb + i * 16] = B[(long long)(n0 + nb + i * 16) * K + (k0 + kk)];
        } else {
            const int nn = tid & 63, kb = tid >> 6;
            #pragma unroll
            for (int i = 0; i < 4; ++i) {
                const int kk = kb * 4 + i;
                Bs[kk][nn] = B[(long long)(k0 + kk) * N + (n0 + nn)];
            }
        }
        __syncthreads();
        #pragma unroll
        for (int kk = 0; kk < 16; ++kk) {
            const float4 a = *(const float4*)&As[kk][ty * 4];
            const float4 b = *(const float4*)&Bs[kk][tx * 4];
            acc[0][0] += a.x * b.x; acc[0][1] += a.x * b.y; acc[0][2] += a.x * b.z; acc[0][3] += a.x * b.w;
            acc[1][0] += a.y * b.x; acc[1][1] += a.y * b.y; acc[1][2] += a.y * b.z; acc[1][3] += a.y * b.w;
            acc[2][0] += a.z * b.x; acc[2][1] += a.z * b.y; acc[2][2] += a.z * b.z; acc[2][3] += a.z * b.w;
            acc[3][0] += a.w * b.x; acc[3][1] += a.w * b.y; acc[3][2] += a.w * b.z; acc[3][3] += a.w * b.w;
        }
        __syncthreads();
    }

    const float* bp = bias ? (bias + (long long)(z & 7) * sbi) : nullptr;
    #pragma unroll
    for (int i = 0; i < 4; ++i) {
        const int m = m0 + ty * 4 + i;
        #pragma unroll
        for (int j = 0; j < 4; ++j) {
            const int n = n0 + tx * 4 + j;
            float v = acc[i][j];
            if (bp) v += BIAS_M ? bp[m] : bp[n];
            if constexpr (ACT == 1) v = act_lrelu(v);
            if constexpr (ACT == 2) v = act_gelu(v);
            if constexpr (sizeof(CT) == 2)
                C[(long long)m * cm + (long long)n * cn] = f2bf(v);
            else
                C[(long long)m * cm + (long long)n * cn] = v;
        }
    }
}

// bf16 MFMA flash attention.
// Q: [32][1024][128] bf16, K: [32][2048][128] bf16, Vt: [32][128][2048] bf16 (pre-transposed)
// O: [32][1024][128] fp32.  grid (16, 32), block 256 (4 waves x 16 q-rows).
__global__ __launch_bounds__(256) void flash_attn_bf16(
    const ushort* __restrict__ Q, const ushort* __restrict__ Kx,
    const ushort* __restrict__ Vt, float* __restrict__ O)
{
    constexpr float SCALE = 0.08838834764831845f;
    const int bh = blockIdx.y;
    const int m0 = blockIdx.x * 64;
    const int tid = threadIdx.x;
    const int lane = tid & 63;
    const int w = tid >> 6;
    const int l15 = lane & 15;
    const int lk8 = (lane >> 4) * 8;   // k-fragment offset
    const int lr4 = (lane >> 4) * 4;   // C/D row group

    __shared__ ushort K_lds[64 * 136];  // [key][d], stride 136 (2-way bank alias)
    __shared__ ushort V_lds[128 * 72];  // [d][key], stride 72
    __shared__ ushort P_lds[64 * 72];   // [qrow][key], stride 72

    const ushort* Qb = Q + (size_t)bh * 1024 * 128;
    const ushort* Kb = Kx + (size_t)bh * 2048 * 128;
    const ushort* Vb = Vt + (size_t)bh * 128 * 2048;

    // Q fragments: wave w owns q-rows m0+w*16 .. +16
    bf16x8 qf[4];
    {
        const int row = m0 + w * 16 + l15;
        #pragma unroll
        for (int ds = 0; ds < 4; ++ds)
            qf[ds] = *(const bf16x8*)(Qb + (size_t)row * 128 + ds * 32 + lk8);
    }

    f32x4 oacc[8];
    #pragma unroll
    for (int i = 0; i < 8; ++i) oacc[i] = f32x4{0.f, 0.f, 0.f, 0.f};
    float mrun[4] = {-1e30f, -1e30f, -1e30f, -1e30f};
    float lrun[4] = {0.f, 0.f, 0.f, 0.f};

    for (int nt = 0; nt < 32; ++nt) {
        const int n0 = nt * 64;
        __syncthreads();   // previous chunk's PV done reading LDS
        #pragma unroll
        for (int it = 0; it < 4; ++it) {   // K: 64x128 = 1024 x short8
            const int u = tid + it * 256;
            const int r = u >> 4, c = (u & 15) * 8;
            *(bf16x8*)&K_lds[r * 136 + c] = *(const bf16x8*)(Kb + (size_t)(n0 + r) * 128 + c);
        }
        #pragma unroll
        for (int it = 0; it < 4; ++it) {   // V^T: 128x64 = 1024 x short8
            const int u = tid + it * 256;
            const int r = u >> 3, c = (u & 7) * 8;
            *(bf16x8*)&V_lds[r * 72 + c] = *(const bf16x8*)(Vb + (size_t)r * 2048 + n0 + c);
        }
        __syncthreads();

        // S = Q K^T: 4 col-tiles of 16 keys
        f32x4 s[4];
        #pragma unroll
        for (int ct = 0; ct < 4; ++ct) {
            s[ct] = f32x4{0.f, 0.f, 0.f, 0.f};
            #pragma unroll
            for (int ds = 0; ds < 4; ++ds) {
                bf16x8 bfr = *(const bf16x8*)&K_lds[(ct * 16 + l15) * 136 + ds * 32 + lk8];
                s[ct] = __builtin_amdgcn_mfma_f32_16x16x32_bf16(qf[ds], bfr, s[ct], 0, 0, 0);
            }
        }

        // online softmax: lane holds rows lr4+j (j=0..3), cols ct*16+l15
        float mx[4], p[4][4], fsc[4];
        #pragma unroll
        for (int j = 0; j < 4; ++j)
            mx[j] = fmaxf(fmaxf(s[0][j], s[1][j]), fmaxf(s[2][j], s[3][j])) * SCALE;
        #pragma unroll
        for (int off = 1; off <= 8; off <<= 1)
            #pragma unroll
            for (int j = 0; j < 4; ++j)
                mx[j] = fmaxf(mx[j], __shfl_xor(mx[j], off));
        #pragma unroll
        for (int j = 0; j < 4; ++j) {
            const float mnew = fmaxf(mrun[j], mx[j]);
            fsc[j] = __expf(mrun[j] - mnew);
            mrun[j] = mnew;
            float sum = 0.f;
            #pragma unroll
            for (int ct = 0; ct < 4; ++ct) {
                const float e = __expf(s[ct][j] * SCALE - mnew);
                p[ct][j] = e;
                sum += e;
            }
            sum += __shfl_xor(sum, 1); sum += __shfl_xor(sum, 2);
            sum += __shfl_xor(sum, 4); sum += __shfl_xor(sum, 8);
            lrun[j] = lrun[j] * fsc[j] + sum;
        }

        // P -> LDS (bf16), per-wave rows only (no cross-wave use)
        #pragma unroll
        for (int j = 0; j < 4; ++j) {
            const int prow = w * 16 + lr4 + j;
            #pragma unroll
            for (int ct = 0; ct < 4; ++ct)
                P_lds[prow * 72 + ct * 16 + l15] = f2bf(p[ct][j]);
        }

        // rescale O, then O += P V
        #pragma unroll
        for (int dt = 0; dt < 8; ++dt)
            #pragma unroll
            for (int j = 0; j < 4; ++j)
                oacc[dt][j] *= fsc[j];
        #pragma unroll
        for (int ks = 0; ks < 2; ++ks) {
            const bf16x8 pa = *(const bf16x8*)&P_lds[(w * 16 + l15) * 72 + ks * 32 + lk8];
            #pragma unroll
            for (int dt = 0; dt < 8; ++dt) {
                const bf16x8 vb = *(const bf16x8*)&V_lds[(dt * 16 + l15) * 72 + ks * 32 + lk8];
                oacc[dt] = __builtin_amdgcn_mfma_f32_16x16x32_bf16(pa, vb, oacc[dt], 0, 0, 0);
            }
        }
    }

    float* Ob = O + (size_t)bh * 1024 * 128;
    #pragma unroll
    for (int j = 0; j < 4; ++j) {
        const float inv = 1.0f / lrun[j];
        const int row = m0 + w * 16 + lr4 + j;
        #pragma unroll
        for (int dt = 0; dt < 8; ++dt)
            Ob[(size_t)row * 128 + dt * 16 + l15] = oacc[dt][j] * inv;
    }
}

extern "C" void kernel_launch(void* const* d_in, const int* in_sizes, int n_in,
                              void* d_out, int out_size, void* d_ws, size_t ws_size,
                              hipStream_t stream)
{
    (void)in_sizes; (void)n_in; (void)out_size; (void)ws_size;
    const float* query = (const float*)d_in[0];
    const float* fts   = (const float*)d_in[1];
    const float* wqc = (const float*)d_in[2];
    const float* bqc = (const float*)d_in[3];
    const float* wq1 = (const float*)d_in[4];
    const float* bq1 = (const float*)d_in[5];
    const float* wq2 = (const float*)d_in[6];
    const float* bq2 = (const float*)d_in[7];
    const float* wk1 = (const float*)d_in[8];
    const float* bk1 = (const float*)d_in[9];
    const float* wk2 = (const float*)d_in[10];
    const float* bk2 = (const float*)d_in[11];
    const float* wv1 = (const float*)d_in[12];
    const float* bv1 = (const float*)d_in[13];
    const float* wv2 = (const float*)d_in[14];
    const float* bv2 = (const float*)d_in[15];
    const float* wo  = (const float*)d_in[16];
    const float* bo  = (const float*)d_in[17];
    const float* wf1 = (const float*)d_in[18];
    const float* bf1 = (const float*)d_in[19];
    const float* wf2 = (const float*)d_in[20];
    const float* bf2 = (const float*)d_in[21];
    float* out = (float*)d_out;

    // ws layout (88 MB used):
    char* ws = (char*)d_ws;
    float*  tbuf  = (float*) (ws + 0LL);          // 32 MB fp32 [65536][128] temps; later xbuf/ybuf
    float*  qh    = (float*) (ws + 33554432LL);   // 16 MB fp32 [32][1024][128]; later enh
    ushort* qbuf  = (ushort*)(ws + 50331648LL);   //  8 MB bf16 [32][1024][128]
    ushort* kbuf  = (ushort*)(ws + 58720256LL);   // 16 MB bf16 [32][2048][128]
    ushort* vbufT = (ushort*)(ws + 75497472LL);   // 16 MB bf16 [32][128][2048]
    float*  enh   = qh;                            // alias (qh dead after step 2)
    float*  xbuf  = tbuf;                          // alias (tbuf dead after step 7)
    float*  ybuf  = (float*)(ws + 16777216LL);    // tbuf+16MB (disjoint from xbuf)

    // 1. q-conv: per (b,head): C[o][hw] = wqc_head @ query_b -> qh[bh][hw][o] (fp32)
    gemm_f32<false, false, 0, true, float><<<dim3(16, 2, 32), 256, 0, stream>>>(
        wqc, query, bqc, qh, 128, 1024, 128,
        0LL, 16384LL, 131072LL, 0LL, 1048576LL, 131072LL, 1, 128, 128);
    // 2. t = lrelu(qh @ wq1^T + bq1)
    gemm_f32<false, true, 1, false, float><<<dim3(2, 512, 1), 256, 0, stream>>>(
        qh, wq1, bq1, tbuf, 32768, 128, 128, 0, 0, 0, 0, 0, 0, 128, 1, 0);
    // 3. qbuf(bf16) = gelu(t @ wq2^T + bq2)
    gemm_f32<false, true, 2, false, ushort><<<dim3(2, 512, 1), 256, 0, stream>>>(
        tbuf, wq2, bq2, qbuf, 32768, 128, 128, 0, 0, 0, 0, 0, 0, 128, 1, 0);
    // 4. t = lrelu(ft @ wk1^T + bk1)
    gemm_f32<true, true, 1, false, float><<<dim3(2, 32, 32), 256, 0, stream>>>(
        fts, wk1, bk1, tbuf, 2048, 128, 128,
        2097152LL, 262144LL, 0, 0, 2097152LL, 262144LL, 128, 1, 0);
    // 5. kbuf(bf16) = gelu(t @ wk2^T + bk2)
    gemm_f32<false, true, 2, false, ushort><<<dim3(2, 1024, 1), 256, 0, stream>>>(
        tbuf, wk2, bk2, kbuf, 65536, 128, 128, 0, 0, 0, 0, 0, 0, 128, 1, 0);
    // 6. t = lrelu(ft @ wv1^T + bv1)
    gemm_f32<true, true, 1, false, float><<<dim3(2, 32, 32), 256, 0, stream>>>(
        fts, wv1, bv1, tbuf, 2048, 128, 128,
        2097152LL, 262144LL, 0, 0, 2097152LL, 262144LL, 128, 1, 0);
    // 7. vbufT(bf16) = gelu(wv2 @ t^T + bv2)^ == v^T[d][key]  (A=wv2, B=t BTRANS)
    gemm_f32<false, true, 2, true, ushort><<<dim3(32, 2, 32), 256, 0, stream>>>(
        wv2, tbuf, bv2, vbufT, 128, 2048, 128,
        0, 0, 2097152LL, 262144LL, 2097152LL, 262144LL, 2048, 1, 0);
    // 8. enh = softmax(q k^T * scale) v   (bf16 MFMA)
    flash_attn_bf16<<<dim3(16, 32), 256, 0, stream>>>(qbuf, kbuf, vbufT, enh);
    // 9. x[b][hw][head*128+o] = enh[bh] @ wo^T + bo
    gemm_f32<false, true, 0, false, float><<<dim3(2, 16, 32), 256, 0, stream>>>(
        enh, wo, bo, xbuf, 1024, 128, 128,
        1048576LL, 131072LL, 0, 0, 1048576LL, 128LL, 1024, 1, 0);
    // 10. y = lrelu(x @ wf1^T + bf1)
    gemm_f32<false, true, 1, false, float><<<dim3(2, 64, 1), 256, 0, stream>>>(
        xbuf, wf1, bf1, ybuf, 4096, 128, 1024, 0, 0, 0, 0, 0, 0, 128, 1, 0);
    // 11. out = lrelu(y @ wf2^T + bf2)
    gemm_f32<false, true, 1, false, float><<<dim3(2, 64, 1), 256, 0, stream>>>(
        ybuf, wf2, bf2, out, 4096, 128, 128, 0, 0, 0, 0, 0, 0, 128, 1, 0);
}

// Round 3
// 377.552 us; speedup vs baseline: 2.6129x; 1.2168x over previous
//
#include <hip/hip_runtime.h>
#include <math.h>

typedef __attribute__((ext_vector_type(8))) __bf16 bf16x8;
typedef __attribute__((ext_vector_type(4))) float f32x4;

__device__ __forceinline__ float act_lrelu(float x) { return x >= 0.0f ? x : 0.01f * x; }
__device__ __forceinline__ float act_gelu(float x) { return 0.5f * x * (1.0f + erff(x * 0.7071067811865475f)); }
__device__ __forceinline__ ushort f2bf(float f) {
    unsigned u = __builtin_bit_cast(unsigned, f);
    u += 0x7fffu + ((u >> 16) & 1u);   // RTNE
    return (ushort)(u >> 16);
}

// ---------------------------------------------------------------------------
// transpose+cast: IN [bz][C][N] f32  ->  OUT [bz][N][C] bf16
__global__ __launch_bounds__(256) void transpose_cast(
    const float* __restrict__ IN, ushort* __restrict__ OUTb, int C, int N)
{
    __shared__ float T[64][68];
    const int tid = threadIdx.x;
    const int r = tid >> 4, c4 = (tid & 15) * 4;
    const int n0 = blockIdx.x * 64, c0 = blockIdx.y * 64;
    const size_t ib = (size_t)blockIdx.z * C * N;
    const size_t ob = (size_t)blockIdx.z * N * C;
    #pragma unroll
    for (int p = 0; p < 4; ++p) {
        const int cl = r + p * 16;
        const float4 v = *(const float4*)&IN[ib + (size_t)(c0 + cl) * N + n0 + c4];
        *(float4*)&T[cl][c4] = v;
    }
    __syncthreads();
    #pragma unroll
    for (int p = 0; p < 4; ++p) {
        const int nl = r + p * 16;
        ushort4 u;
        u.x = f2bf(T[c4 + 0][nl]);
        u.y = f2bf(T[c4 + 1][nl]);
        u.z = f2bf(T[c4 + 2][nl]);
        u.w = f2bf(T[c4 + 3][nl]);
        *(ushort4*)&OUTb[ob + (size_t)(n0 + nl) * C + c0 + c4] = u;
    }
}

// ---------------------------------------------------------------------------
// shared MFMA helpers
// W in LDS padded [128][136] bf16. layer8: acc[nt] += A(16x128) * W^T tile nt.
__device__ __forceinline__ void layer8(const bf16x8 a[4], const ushort* Wl,
                                       f32x4 acc[8], int l15, int lk8)
{
    #pragma unroll
    for (int ds = 0; ds < 4; ++ds)
        #pragma unroll
        for (int nt = 0; nt < 8; ++nt) {
            const bf16x8 b = *(const bf16x8*)&Wl[(nt * 16 + l15) * 136 + ds * 32 + lk8];
            acc[nt] = __builtin_amdgcn_mfma_f32_16x16x32_bf16(a[ds], b, acc[nt], 0, 0, 0);
        }
}

// acc (+bias, act) -> bf16 -> wave-local t_lds[16][136] -> A-fragments for next layer
template <int ACT>
__device__ __forceinline__ void retile(const f32x4 acc[8], const float bias[8], ushort* tl,
                                       int l15, int lr4, int lk8, bf16x8 a[4])
{
    #pragma unroll
    for (int nt = 0; nt < 8; ++nt)
        #pragma unroll
        for (int j = 0; j < 4; ++j) {
            float v = acc[nt][j] + bias[nt];
            if constexpr (ACT == 1) v = act_lrelu(v);
            if constexpr (ACT == 2) v = act_gelu(v);
            tl[(lr4 + j) * 136 + nt * 16 + l15] = f2bf(v);
        }
    #pragma unroll
    for (int ds = 0; ds < 4; ++ds)
        a[ds] = *(const bf16x8*)&tl[l15 * 136 + ds * 32 + lk8];
}

// stage f32 weight [128][128] (row stride ldw) -> LDS bf16 padded [128][136]
__device__ __forceinline__ void stage_w(const float* __restrict__ W, int ldw,
                                        ushort* Wl, int tid)
{
    #pragma unroll
    for (int it = 0; it < 16; ++it) {
        const int i = tid * 4 + it * 1024;
        const int r = i >> 7, c = i & 127;
        const float4 v = *(const float4*)&W[(size_t)r * ldw + c];
        ushort* p = &Wl[r * 136 + c];
        p[0] = f2bf(v.x); p[1] = f2bf(v.y); p[2] = f2bf(v.z); p[3] = f2bf(v.w);
    }
}

// ---------------------------------------------------------------------------
// fused 2-layer MLP: Y = act2(act1(X@W1^T+b1)@W2^T+b2).  X,Y bf16 [R][128].
// OUTT: write Y transposed per-bh: Vt[bh][col][key], bh = row>>11, key = row&2047.
// block 256 (4 waves x 64 rows), grid R/256.
template <int ACT1, int ACT2, bool OUTT>
__global__ __launch_bounds__(256) void mlp2_kernel(
    const ushort* __restrict__ X,
    const float* __restrict__ W1, const float* __restrict__ B1,
    const float* __restrict__ W2, const float* __restrict__ B2,
    ushort* __restrict__ Y)
{
    __shared__ ushort W1l[128 * 136], W2l[128 * 136];
    __shared__ ushort tl[4][16 * 136];
    const int tid = threadIdx.x, lane = tid & 63, w = tid >> 6;
    const int l15 = lane & 15, lk8 = (lane >> 4) * 8, lr4 = (lane >> 4) * 4;
    stage_w(W1, 128, W1l, tid);
    stage_w(W2, 128, W2l, tid);
    float b1[8], b2[8];
    #pragma unroll
    for (int nt = 0; nt < 8; ++nt) { b1[nt] = B1[nt * 16 + l15]; b2[nt] = B2[nt * 16 + l15]; }
    __syncthreads();

    const int m0 = blockIdx.x * 256 + w * 64;
    const f32x4 z = {0.f, 0.f, 0.f, 0.f};
    #pragma unroll
    for (int rf = 0; rf < 4; ++rf) {
        const int row = m0 + rf * 16;
        bf16x8 a[4];
        #pragma unroll
        for (int ds = 0; ds < 4; ++ds)
            a[ds] = *(const bf16x8*)(X + (size_t)(row + l15) * 128 + ds * 32 + lk8);
        f32x4 acc[8];
        #pragma unroll
        for (int i = 0; i < 8; ++i) acc[i] = z;
        layer8(a, W1l, acc, l15, lk8);
        bf16x8 a2[4];
        retile<ACT1>(acc, b1, tl[w], l15, lr4, lk8, a2);
        f32x4 acc2[8];
        #pragma unroll
        for (int i = 0; i < 8; ++i) acc2[i] = z;
        layer8(a2, W2l, acc2, l15, lk8);
        if constexpr (!OUTT) {
            #pragma unroll
            for (int nt = 0; nt < 8; ++nt)
                #pragma unroll
                for (int j = 0; j < 4; ++j) {
                    float v = acc2[nt][j] + b2[nt];
                    if constexpr (ACT2 == 1) v = act_lrelu(v);
                    if constexpr (ACT2 == 2) v = act_gelu(v);
                    Y[(size_t)(row + lr4 + j) * 128 + nt * 16 + l15] = f2bf(v);
                }
        } else {
            const int R0 = row + lr4;
            const int bh = R0 >> 11, key = R0 & 2047;
            #pragma unroll
            for (int nt = 0; nt < 8; ++nt) {
                ushort4 pk;
                #pragma unroll
                for (int j = 0; j < 4; ++j) {
                    float v = acc2[nt][j] + b2[nt];
                    if constexpr (ACT2 == 1) v = act_lrelu(v);
                    if constexpr (ACT2 == 2) v = act_gelu(v);
                    (&pk.x)[j] = f2bf(v);
                }
                *(ushort4*)&Y[((size_t)bh * 128 + nt * 16 + l15) * 2048 + key] = pk;
            }
        }
    }
}

// ---------------------------------------------------------------------------
// fused q-path: qh = X@wqc_h^T+bqc_h (per-head), t = lrelu(qh@wq1^T+b1),
// q = gelu(t@wq2^T+b2).  X = queryT [4][1024][128] bf16, Y [32][1024][128] bf16.
// grid 256 (8 blocks of 128 rows per bh), block 256 (4 waves x 32 rows).
__global__ __launch_bounds__(256) void mlp3_kernel(
    const ushort* __restrict__ X,
    const float* __restrict__ W0, const float* __restrict__ B0,
    const float* __restrict__ W1, const float* __restrict__ B1,
    const float* __restrict__ W2, const float* __restrict__ B2,
    ushort* __restrict__ Y)
{
    __shared__ ushort W0l[128 * 136], W1l[128 * 136], W2l[128 * 136];
    __shared__ ushort tl[4][16 * 136];
    const int tid = threadIdx.x, lane = tid & 63, w = tid >> 6;
    const int l15 = lane & 15, lk8 = (lane >> 4) * 8, lr4 = (lane >> 4) * 4;
    const int bh = blockIdx.x >> 3;
    const int head = bh & 7, b = bh >> 3;
    const int hw0 = (blockIdx.x & 7) * 128;
    stage_w(W0 + (size_t)head * 128 * 128, 128, W0l, tid);
    stage_w(W1, 128, W1l, tid);
    stage_w(W2, 128, W2l, tid);
    float b0[8], b1[8], b2[8];
    #pragma unroll
    for (int nt = 0; nt < 8; ++nt) {
        b0[nt] = B0[head * 128 + nt * 16 + l15];
        b1[nt] = B1[nt * 16 + l15];
        b2[nt] = B2[nt * 16 + l15];
    }
    __syncthreads();

    const f32x4 z = {0.f, 0.f, 0.f, 0.f};
    #pragma unroll
    for (int rf = 0; rf < 2; ++rf) {
        const int r_loc = hw0 + w * 32 + rf * 16;
        bf16x8 a[4];
        #pragma unroll
        for (int ds = 0; ds < 4; ++ds)
            a[ds] = *(const bf16x8*)(X + ((size_t)b * 1024 + r_loc + l15) * 128 + ds * 32 + lk8);
        f32x4 acc[8];
        #pragma unroll
        for (int i = 0; i < 8; ++i) acc[i] = z;
        layer8(a, W0l, acc, l15, lk8);
        bf16x8 a2[4];
        retile<0>(acc, b0, tl[w], l15, lr4, lk8, a2);
        #pragma unroll
        for (int i = 0; i < 8; ++i) acc[i] = z;
        layer8(a2, W1l, acc, l15, lk8);
        bf16x8 a3[4];
        retile<1>(acc, b1, tl[w], l15, lr4, lk8, a3);
        #pragma unroll
        for (int i = 0; i < 8; ++i) acc[i] = z;
        layer8(a3, W2l, acc, l15, lk8);
        #pragma unroll
        for (int nt = 0; nt < 8; ++nt)
            #pragma unroll
            for (int j = 0; j < 4; ++j)
                Y[((size_t)bh * 1024 + r_loc + lr4 + j) * 128 + nt * 16 + l15] =
                    f2bf(act_gelu(acc[nt][j] + b2[nt]));
    }
}

// ---------------------------------------------------------------------------
// fused output path: per-head x_h = enh_h@wo^T+bo (no act), y += x_h@wf1_h^T;
// y = lrelu(y+bf1); out = lrelu(y@wf2^T+bf2).  E bf16 [32][1024][128], OUT f32.
// grid 64 (b*16 + hwtile), block 256 (4 waves x 16 rows).
__global__ __launch_bounds__(256) void outpath_kernel(
    const ushort* __restrict__ E,
    const float* __restrict__ Wo, const float* __restrict__ Bo,
    const float* __restrict__ Wf1, const float* __restrict__ Bf1,
    const float* __restrict__ Wf2, const float* __restrict__ Bf2,
    float* __restrict__ OUT)
{
    __shared__ ushort Wol[128 * 136], W1l[128 * 136], W2l[128 * 136];
    __shared__ ushort tl[4][16 * 136];
    const int tid = threadIdx.x, lane = tid & 63, w = tid >> 6;
    const int l15 = lane & 15, lk8 = (lane >> 4) * 8, lr4 = (lane >> 4) * 4;
    const int b = blockIdx.x >> 4;
    const int m0 = (blockIdx.x & 15) * 64;
    stage_w(Wo, 128, Wol, tid);
    stage_w(Wf2, 128, W2l, tid);
    float bo_[8], b1_[8], b2_[8];
    #pragma unroll
    for (int nt = 0; nt < 8; ++nt) {
        bo_[nt] = Bo[nt * 16 + l15];
        b1_[nt] = Bf1[nt * 16 + l15];
        b2_[nt] = Bf2[nt * 16 + l15];
    }
    const f32x4 z = {0.f, 0.f, 0.f, 0.f};
    f32x4 yacc[8];
    #pragma unroll
    for (int i = 0; i < 8; ++i) yacc[i] = z;

    for (int h = 0; h < 8; ++h) {
        __syncthreads();                      // prior reads of W1l complete
        stage_w(Wf1 + h * 128, 1024, W1l, tid);
        __syncthreads();                      // W1l (and, first iter, Wol/W2l) visible
        bf16x8 a[4];
        const size_t erow = ((size_t)(b * 8 + h) * 1024 + m0 + w * 16 + l15) * 128;
        #pragma unroll
        for (int ds = 0; ds < 4; ++ds)
            a[ds] = *(const bf16x8*)(E + erow + ds * 32 + lk8);
        f32x4 xacc[8];
        #pragma unroll
        for (int i = 0; i < 8; ++i) xacc[i] = z;
        layer8(a, Wol, xacc, l15, lk8);
        bf16x8 a2[4];
        retile<0>(xacc, bo_, tl[w], l15, lr4, lk8, a2);
        layer8(a2, W1l, yacc, l15, lk8);      // accumulate over heads
    }
    bf16x8 a3[4];
    retile<1>(yacc, b1_, tl[w], l15, lr4, lk8, a3);
    f32x4 oacc[8];
    #pragma unroll
    for (int i = 0; i < 8; ++i) oacc[i] = z;
    layer8(a3, W2l, oacc, l15, lk8);
    #pragma unroll
    for (int nt = 0; nt < 8; ++nt)
        #pragma unroll
        for (int j = 0; j < 4; ++j)
            OUT[((size_t)b * 1024 + m0 + w * 16 + lr4 + j) * 128 + nt * 16 + l15] =
                act_lrelu(oacc[nt][j] + b2_[nt]);
}

// ---------------------------------------------------------------------------
// bf16 MFMA flash attention, double-buffered K/V with async-stage split.
// Q [32][1024][128], K [32][2048][128], Vt [32][128][2048], O bf16 [32][1024][128]
__global__ __launch_bounds__(256, 2) void flash_attn_bf16(
    const ushort* __restrict__ Q, const ushort* __restrict__ Kx,
    const ushort* __restrict__ Vt, ushort* __restrict__ O)
{
    constexpr float SCALE = 0.08838834764831845f;
    const int bh = blockIdx.y;
    const int m0 = blockIdx.x * 64;
    const int tid = threadIdx.x;
    const int lane = tid & 63, w = tid >> 6;
    const int l15 = lane & 15, lk8 = (lane >> 4) * 8, lr4 = (lane >> 4) * 4;

    __shared__ ushort K_lds[2][64 * 136];
    __shared__ ushort V_lds[2][128 * 72];
    __shared__ ushort P_lds[64 * 72];

    const ushort* Qb = Q + (size_t)bh * 1024 * 128;
    const ushort* Kb = Kx + (size_t)bh * 2048 * 128;
    const ushort* Vb = Vt + (size_t)bh * 128 * 2048;

    bf16x8 qf[4];
    {
        const int row = m0 + w * 16 + l15;
        #pragma unroll
        for (int ds = 0; ds < 4; ++ds)
            qf[ds] = *(const bf16x8*)(Qb + (size_t)row * 128 + ds * 32 + lk8);
    }

    const int kr = tid >> 4, kc = (tid & 15) * 8;   // K staging: +16 rows per it
    const int vr = tid >> 3, vc = (tid & 7) * 8;    // V staging: +32 rows per it
    bf16x8 kreg[4], vreg[4];
    #pragma unroll
    for (int it = 0; it < 4; ++it) {
        kreg[it] = *(const bf16x8*)(Kb + (size_t)(kr + it * 16) * 128 + kc);
        vreg[it] = *(const bf16x8*)(Vb + (size_t)(vr + it * 32) * 2048 + vc);
    }
    #pragma unroll
    for (int it = 0; it < 4; ++it) {
        *(bf16x8*)&K_lds[0][(kr + it * 16) * 136 + kc] = kreg[it];
        *(bf16x8*)&V_lds[0][(vr + it * 32) * 72 + vc] = vreg[it];
    }
    __syncthreads();

    f32x4 oacc[8];
    #pragma unroll
    for (int i = 0; i < 8; ++i) oacc[i] = f32x4{0.f, 0.f, 0.f, 0.f};
    float mrun[4] = {-1e30f, -1e30f, -1e30f, -1e30f};
    float lrun[4] = {0.f, 0.f, 0.f, 0.f};
    int cur = 0;

    for (int nt = 0; nt < 32; ++nt) {
        if (nt < 31) {                       // issue next chunk's loads early
            const int n1 = (nt + 1) * 64;
            #pragma unroll
            for (int it = 0; it < 4; ++it) {
                kreg[it] = *(const bf16x8*)(Kb + (size_t)(n1 + kr + it * 16) * 128 + kc);
                vreg[it] = *(const bf16x8*)(Vb + (size_t)(vr + it * 32) * 2048 + n1 + vc);
            }
        }
        const ushort* Kc = &K_lds[cur][0];
        const ushort* Vc = &V_lds[cur][0];

        f32x4 s[4];
        #pragma unroll
        for (int i = 0; i < 4; ++i) s[i] = f32x4{0.f, 0.f, 0.f, 0.f};
        __builtin_amdgcn_s_setprio(1);
        #pragma unroll
        for (int ds = 0; ds < 4; ++ds)
            #pragma unroll
            for (int ct = 0; ct < 4; ++ct) {
                const bf16x8 bfr = *(const bf16x8*)&Kc[(ct * 16 + l15) * 136 + ds * 32 + lk8];
                s[ct] = __builtin_amdgcn_mfma_f32_16x16x32_bf16(qf[ds], bfr, s[ct], 0, 0, 0);
            }
        __builtin_amdgcn_s_setprio(0);

        // online softmax: lane holds rows lr4+j, cols ct*16+l15
        float mx[4], p[4][4], fsc[4];
        #pragma unroll
        for (int j = 0; j < 4; ++j)
            mx[j] = fmaxf(fmaxf(s[0][j], s[1][j]), fmaxf(s[2][j], s[3][j])) * SCALE;
        #pragma unroll
        for (int off = 1; off <= 8; off <<= 1)
            #pragma unroll
            for (int j = 0; j < 4; ++j)
                mx[j] = fmaxf(mx[j], __shfl_xor(mx[j], off));
        #pragma unroll
        for (int j = 0; j < 4; ++j) {
            const float mnew = fmaxf(mrun[j], mx[j]);
            fsc[j] = __expf(mrun[j] - mnew);
            mrun[j] = mnew;
            float sum = 0.f;
            #pragma unroll
            for (int ct = 0; ct < 4; ++ct) {
                const float e = __expf(s[ct][j] * SCALE - mnew);
                p[ct][j] = e;
                sum += e;
            }
            sum += __shfl_xor(sum, 1); sum += __shfl_xor(sum, 2);
            sum += __shfl_xor(sum, 4); sum += __shfl_xor(sum, 8);
            lrun[j] = lrun[j] * fsc[j] + sum;
        }
        #pragma unroll
        for (int j = 0; j < 4; ++j) {
            const int prow = w * 16 + lr4 + j;
            #pragma unroll
            for (int ct = 0; ct < 4; ++ct)
                P_lds[prow * 72 + ct * 16 + l15] = f2bf(p[ct][j]);
        }
        #pragma unroll
        for (int dt = 0; dt < 8; ++dt)
            #pragma unroll
            for (int j = 0; j < 4; ++j)
                oacc[dt][j] *= fsc[j];

        __builtin_amdgcn_s_setprio(1);
        #pragma unroll
        for (int ks = 0; ks < 2; ++ks) {
            const bf16x8 pa = *(const bf16x8*)&P_lds[(w * 16 + l15) * 72 + ks * 32 + lk8];
            #pragma unroll
            for (int dt = 0; dt < 8; ++dt) {
                const bf16x8 vb = *(const bf16x8*)&Vc[(dt * 16 + l15) * 72 + ks * 32 + lk8];
                oacc[dt] = __builtin_amdgcn_mfma_f32_16x16x32_bf16(pa, vb, oacc[dt], 0, 0, 0);
            }
        }
        __builtin_amdgcn_s_setprio(0);

        if (nt < 31) {                       // write next chunk (other buffer)
            const int nxt = cur ^ 1;
            #pragma unroll
            for (int it = 0; it < 4; ++it) {
                *(bf16x8*)&K_lds[nxt][(kr + it * 16) * 136 + kc] = kreg[it];
                *(bf16x8*)&V_lds[nxt][(vr + it * 32) * 72 + vc] = vreg[it];
            }
        }
        __syncthreads();
        cur ^= 1;
    }

    ushort* Ob = O + (size_t)bh * 1024 * 128;
    #pragma unroll
    for (int j = 0; j < 4; ++j) {
        const float inv = 1.0f / lrun[j];
        const int row = m0 + w * 16 + lr4 + j;
        #pragma unroll
        for (int dt = 0; dt < 8; ++dt)
            Ob[(size_t)row * 128 + dt * 16 + l15] = f2bf(oacc[dt][j] * inv);
    }
}

// ---------------------------------------------------------------------------
extern "C" void kernel_launch(void* const* d_in, const int* in_sizes, int n_in,
                              void* d_out, int out_size, void* d_ws, size_t ws_size,
                              hipStream_t stream)
{
    (void)in_sizes; (void)n_in; (void)out_size; (void)ws_size;
    const float* query = (const float*)d_in[0];
    const float* fts   = (const float*)d_in[1];
    const float* wqc = (const float*)d_in[2];
    const float* bqc = (const float*)d_in[3];
    const float* wq1 = (const float*)d_in[4];
    const float* bq1 = (const float*)d_in[5];
    const float* wq2 = (const float*)d_in[6];
    const float* bq2 = (const float*)d_in[7];
    const float* wk1 = (const float*)d_in[8];
    const float* bk1 = (const float*)d_in[9];
    const float* wk2 = (const float*)d_in[10];
    const float* bk2 = (const float*)d_in[11];
    const float* wv1 = (const float*)d_in[12];
    const float* bv1 = (const float*)d_in[13];
    const float* wv2 = (const float*)d_in[14];
    const float* bv2 = (const float*)d_in[15];
    const float* wo  = (const float*)d_in[16];
    const float* bo  = (const float*)d_in[17];
    const float* wf1 = (const float*)d_in[18];
    const float* bf1 = (const float*)d_in[19];
    const float* wf2 = (const float*)d_in[20];
    const float* bf2 = (const float*)d_in[21];
    float* out = (float*)d_out;

    // ws layout (65 MB used)
    char* ws = (char*)d_ws;
    ushort* ftb    = (ushort*)(ws + 0LL);          // 16 MB bf16 [32][2048][128]
    ushort* queryT = (ushort*)(ws + 16777216LL);   //  1 MB bf16 [4][1024][128]
    ushort* qbuf   = (ushort*)(ws + 17825792LL);   //  8 MB bf16 [32][1024][128]
    ushort* kbuf   = (ushort*)(ws + 26214400LL);   // 16 MB bf16 [32][2048][128]
    ushort* vbufT  = (ushort*)(ws + 42991616LL);   // 16 MB bf16 [32][128][2048]
    ushort* enh    = (ushort*)(ws + 59768832LL);   //  8 MB bf16 [32][1024][128]

    // 1. ft = fts^T (bf16)
    transpose_cast<<<dim3(32, 2, 32), 256, 0, stream>>>(fts, ftb, 128, 2048);
    // 2. queryT = query^T (bf16)
    transpose_cast<<<dim3(16, 2, 4), 256, 0, stream>>>(query, queryT, 128, 1024);
    // 3. q-path: qconv + 2-layer MLP
    mlp3_kernel<<<256, 256, 0, stream>>>(queryT, wqc, bqc, wq1, bq1, wq2, bq2, qbuf);
    // 4. k-path
    mlp2_kernel<1, 2, false><<<256, 256, 0, stream>>>(ftb, wk1, bk1, wk2, bk2, kbuf);
    // 5. v-path (transposed output)
    mlp2_kernel<1, 2, true><<<256, 256, 0, stream>>>(ftb, wv1, bv1, wv2, bv2, vbufT);
    // 6. attention
    flash_attn_bf16<<<dim3(16, 32), 256, 0, stream>>>(qbuf, kbuf, vbufT, enh);
    // 7. output path: proj_out + head concat + final 2-layer MLP
    outpath_kernel<<<64, 256, 0, stream>>>(enh, wo, bo, wf1, bf1, wf2, bf2, out);
}

// Round 4
// 317.721 us; speedup vs baseline: 3.1049x; 1.1883x over previous
//
#include <hip/hip_runtime.h>
#include <math.h>

typedef __attribute__((ext_vector_type(8))) __bf16 bf16x8;
typedef __attribute__((ext_vector_type(4))) float f32x4;

__device__ __forceinline__ float act_lrelu(float x) { return x >= 0.0f ? x : 0.01f * x; }
__device__ __forceinline__ float act_gelu(float x) { return 0.5f * x * (1.0f + erff(x * 0.7071067811865475f)); }
__device__ __forceinline__ ushort f2bf(float f) {
    unsigned u = __builtin_bit_cast(unsigned, f);
    u += 0x7fffu + ((u >> 16) & 1u);   // RTNE
    return (ushort)(u >> 16);
}

// ---------------------------------------------------------------------------
// prep: (a) convert weights f32->bf16, (b) Wcomb_h = wf1_h @ wo (bf16),
// (c) bconst = bf1 + sum_h wf1_h @ bo (f32).  grid 69, block 256.
__global__ __launch_bounds__(256) void prep_kernel(
    const float* __restrict__ wqc, const float* __restrict__ wq1,
    const float* __restrict__ wq2, const float* __restrict__ wk1,
    const float* __restrict__ wk2, const float* __restrict__ wv1,
    const float* __restrict__ wv2, const float* __restrict__ wf2,
    const float* __restrict__ wf1, const float* __restrict__ wo,
    const float* __restrict__ bo, const float* __restrict__ bf1,
    ushort* __restrict__ Wdst, ushort* __restrict__ Wcomb,
    float* __restrict__ bconst)
{
    __shared__ float smem[32768];   // 128 KB: woL[16384] + wfL[16384]
    const int tid = threadIdx.x;
    const int blk = blockIdx.x;
    if (blk < 60) {                 // straight converts (m is block-uniform)
        #pragma unroll
        for (int p = 0; p < 4; ++p) {
            const int lin = blk * 4096 + p * 1024 + tid * 4;
            const float* s;
            if (lin < 131072) s = wqc + lin;
            else {
                const int m = (lin - 131072) >> 14, idx = (lin - 131072) & 16383;
                s = (m == 0) ? wq1 + idx : (m == 1) ? wq2 + idx : (m == 2) ? wk1 + idx :
                    (m == 3) ? wk2 + idx : (m == 4) ? wv1 + idx : (m == 5) ? wv2 + idx
                             : wf2 + idx;
            }
            const float4 v = *(const float4*)s;
            ushort4 u; u.x = f2bf(v.x); u.y = f2bf(v.y); u.z = f2bf(v.z); u.w = f2bf(v.w);
            *(ushort4*)&Wdst[lin] = u;
        }
    } else if (blk < 68) {          // Wcomb for head h
        const int h = blk - 60;
        float* woL = smem;
        float* wfL = smem + 16384;
        #pragma unroll
        for (int it = 0; it < 16; ++it) {
            const int lin = (tid + it * 256) * 4;
            *(float4*)&woL[lin] = *(const float4*)&wo[lin];
            const int r = lin >> 7, c = lin & 127;
            *(float4*)&wfL[lin] = *(const float4*)&wf1[r * 1024 + h * 128 + c];
        }
        __syncthreads();
        const int j = tid & 127, half = tid >> 7;
        float acc[64] = {};
        for (int k = 0; k < 128; ++k) {
            const float a = wfL[j * 128 + k];
            #pragma unroll
            for (int c = 0; c < 64; ++c)
                acc[c] += a * woL[k * 128 + half * 64 + c];
        }
        #pragma unroll
        for (int c = 0; c < 64; ++c)
            Wcomb[h * 16384 + j * 128 + half * 64 + c] = f2bf(acc[c]);
    } else {                        // bconst
        const int j = tid & 127, kh = tid >> 7;
        float acc = (kh == 0) ? bf1[j] : 0.f;
        for (int k = kh * 512; k < kh * 512 + 512; ++k)
            acc += wf1[j * 1024 + k] * bo[k & 127];
        smem[tid] = acc;
        __syncthreads();
        if (tid < 128) bconst[j] = smem[j] + smem[j + 128];
    }
}

// ---------------------------------------------------------------------------
// transpose+cast: IN [bz][C][N] f32  ->  OUT [bz][N][C] bf16
__global__ __launch_bounds__(256) void transpose_cast(
    const float* __restrict__ IN, ushort* __restrict__ OUTb, int C, int N)
{
    __shared__ float T[64][68];
    const int tid = threadIdx.x;
    const int r = tid >> 4, c4 = (tid & 15) * 4;
    const int n0 = blockIdx.x * 64, c0 = blockIdx.y * 64;
    const size_t ib = (size_t)blockIdx.z * C * N;
    const size_t ob = (size_t)blockIdx.z * N * C;
    #pragma unroll
    for (int p = 0; p < 4; ++p) {
        const int cl = r + p * 16;
        const float4 v = *(const float4*)&IN[ib + (size_t)(c0 + cl) * N + n0 + c4];
        *(float4*)&T[cl][c4] = v;
    }
    __syncthreads();
    #pragma unroll
    for (int p = 0; p < 4; ++p) {
        const int nl = r + p * 16;
        ushort4 u;
        u.x = f2bf(T[c4 + 0][nl]);
        u.y = f2bf(T[c4 + 1][nl]);
        u.z = f2bf(T[c4 + 2][nl]);
        u.w = f2bf(T[c4 + 3][nl]);
        *(ushort4*)&OUTb[ob + (size_t)(n0 + nl) * C + c0 + c4] = u;
    }
}

// ---------------------------------------------------------------------------
// swizzled-LDS MFMA helpers. W LDS layout: [128][128] ushort, element (r,c)
// stored at r*128 + (c ^ ((r&7)<<3))  -> 16B chunks spread over 8 bank slots.
__device__ __forceinline__ void stage_wbf(const ushort* __restrict__ Wg,
                                          ushort* Wl, int tid)
{
    #pragma unroll
    for (int it = 0; it < 8; ++it) {
        const int lin = (tid + it * 256) * 8;
        const int r = lin >> 7, c = lin & 127;
        const bf16x8 v = *(const bf16x8*)&Wg[lin];
        *(bf16x8*)&Wl[r * 128 + (c ^ ((r & 7) << 3))] = v;
    }
}

__device__ __forceinline__ void layer8swz(const bf16x8 a[4], const ushort* Wl,
                                          f32x4 acc[8], int l15, int lk8)
{
    const int sx = (l15 & 7) << 3;
    #pragma unroll
    for (int ds = 0; ds < 4; ++ds) {
        const int cb = (ds * 32 + lk8) ^ sx;
        #pragma unroll
        for (int nt = 0; nt < 8; ++nt) {
            const bf16x8 b = *(const bf16x8*)&Wl[(nt * 16 + l15) * 128 + cb];
            acc[nt] = __builtin_amdgcn_mfma_f32_16x16x32_bf16(a[ds], b, acc[nt], 0, 0, 0);
        }
    }
}

// acc (+bias, act) -> bf16 -> wave-local swizzled tl[16][128] -> next A-frags
template <int ACT>
__device__ __forceinline__ void retile_swz(const f32x4 acc[8], const float bias[8],
                                           ushort* tlw, int l15, int lr4, int lk8,
                                           bf16x8 aout[4])
{
    #pragma unroll
    for (int nt = 0; nt < 8; ++nt)
        #pragma unroll
        for (int j = 0; j < 4; ++j) {
            float v = acc[nt][j] + bias[nt];
            if constexpr (ACT == 1) v = act_lrelu(v);
            if constexpr (ACT == 2) v = act_gelu(v);
            const int row = lr4 + j;
            tlw[row * 128 + ((nt * 16 + l15) ^ ((row & 7) << 3))] = f2bf(v);
        }
    const int sx = (l15 & 7) << 3;
    #pragma unroll
    for (int ds = 0; ds < 4; ++ds)
        aout[ds] = *(const bf16x8*)&tlw[l15 * 128 + ((ds * 32 + lk8) ^ sx)];
}

// ---------------------------------------------------------------------------
// mlp1: Y = X @ W_head^T + B_head (no act). 128 rows/block, grid rows/128.
// QMAP: X row r -> (r>>13)*1024 + (r&1023)  (qh-space -> queryT-space)
template <bool QMAP>
__global__ __launch_bounds__(256) void mlp1v(
    const ushort* __restrict__ X, const ushort* __restrict__ Wbf,
    const float* __restrict__ Bf, ushort* __restrict__ Y)
{
    __shared__ ushort Wl[128 * 128];
    const int tid = threadIdx.x, lane = tid & 63, w = tid >> 6;
    const int l15 = lane & 15, lk8 = (lane >> 4) * 8, lr4 = (lane >> 4) * 4;
    const int head = (blockIdx.x >> 3) & 7;
    stage_wbf(Wbf + head * 16384, Wl, tid);
    float b0[8];
    #pragma unroll
    for (int nt = 0; nt < 8; ++nt) b0[nt] = Bf[head * 128 + nt * 16 + l15];

    const int m0 = blockIdx.x * 128 + w * 32;
    bf16x8 a0[4], a1[4];
    #pragma unroll
    for (int ds = 0; ds < 4; ++ds) {
        int r0 = m0 + l15, r1 = m0 + 16 + l15;
        if constexpr (QMAP) { r0 = (r0 >> 13) * 1024 + (r0 & 1023); r1 = (r1 >> 13) * 1024 + (r1 & 1023); }
        a0[ds] = *(const bf16x8*)(X + (size_t)r0 * 128 + ds * 32 + lk8);
        a1[ds] = *(const bf16x8*)(X + (size_t)r1 * 128 + ds * 32 + lk8);
    }
    __syncthreads();
    const f32x4 z = {0.f, 0.f, 0.f, 0.f};
    #pragma unroll
    for (int rf = 0; rf < 2; ++rf) {
        f32x4 acc[8];
        #pragma unroll
        for (int i = 0; i < 8; ++i) acc[i] = z;
        layer8swz(rf ? a1 : a0, Wl, acc, l15, lk8);
        const int row = m0 + rf * 16;
        #pragma unroll
        for (int nt = 0; nt < 8; ++nt)
            #pragma unroll
            for (int j = 0; j < 4; ++j)
                Y[(size_t)(row + lr4 + j) * 128 + nt * 16 + l15] = f2bf(acc[nt][j] + b0[nt]);
    }
}

// ---------------------------------------------------------------------------
// mlp2: Y = act2(act1(X@W1^T+b1)@W2^T+b2). 128 rows/block. bf16 weights.
// OUTT: Vt[bh][col][key] transposed write (bh = row>>11, key = row&2047).
template <int ACT1, int ACT2, bool OUTT>
__global__ __launch_bounds__(256) void mlp2v(
    const ushort* __restrict__ X,
    const ushort* __restrict__ W1bf, const float* __restrict__ B1,
    const ushort* __restrict__ W2bf, const float* __restrict__ B2,
    ushort* __restrict__ Y)
{
    __shared__ ushort W1l[128 * 128], W2l[128 * 128];
    __shared__ ushort tl[4][16 * 128];
    const int tid = threadIdx.x, lane = tid & 63, w = tid >> 6;
    const int l15 = lane & 15, lk8 = (lane >> 4) * 8, lr4 = (lane >> 4) * 4;
    stage_wbf(W1bf, W1l, tid);
    stage_wbf(W2bf, W2l, tid);
    float b1[8], b2[8];
    #pragma unroll
    for (int nt = 0; nt < 8; ++nt) { b1[nt] = B1[nt * 16 + l15]; b2[nt] = B2[nt * 16 + l15]; }

    const int m0 = blockIdx.x * 128 + w * 32;
    bf16x8 a0[4], a1[4];
    #pragma unroll
    for (int ds = 0; ds < 4; ++ds) {
        a0[ds] = *(const bf16x8*)(X + (size_t)(m0 + l15) * 128 + ds * 32 + lk8);
        a1[ds] = *(const bf16x8*)(X + (size_t)(m0 + 16 + l15) * 128 + ds * 32 + lk8);
    }
    __syncthreads();
    const f32x4 z = {0.f, 0.f, 0.f, 0.f};
    #pragma unroll
    for (int rf = 0; rf < 2; ++rf) {
        const int row = m0 + rf * 16;
        f32x4 acc[8];
        #pragma unroll
        for (int i = 0; i < 8; ++i) acc[i] = z;
        layer8swz(rf ? a1 : a0, W1l, acc, l15, lk8);
        bf16x8 a2[4];
        retile_swz<ACT1>(acc, b1, tl[w], l15, lr4, lk8, a2);
        f32x4 acc2[8];
        #pragma unroll
        for (int i = 0; i < 8; ++i) acc2[i] = z;
        layer8swz(a2, W2l, acc2, l15, lk8);
        if constexpr (!OUTT) {
            #pragma unroll
            for (int nt = 0; nt < 8; ++nt)
                #pragma unroll
                for (int j = 0; j < 4; ++j) {
                    float v = acc2[nt][j] + b2[nt];
                    if constexpr (ACT2 == 1) v = act_lrelu(v);
                    if constexpr (ACT2 == 2) v = act_gelu(v);
                    Y[(size_t)(row + lr4 + j) * 128 + nt * 16 + l15] = f2bf(v);
                }
        } else {
            const int R0 = row + lr4;
            const int bh = R0 >> 11, key = R0 & 2047;
            #pragma unroll
            for (int nt = 0; nt < 8; ++nt) {
                ushort4 pk;
                #pragma unroll
                for (int j = 0; j < 4; ++j) {
                    float v = acc2[nt][j] + b2[nt];
                    if constexpr (ACT2 == 1) v = act_lrelu(v);
                    if constexpr (ACT2 == 2) v = act_gelu(v);
                    (&pk.x)[j] = f2bf(v);
                }
                *(ushort4*)&Y[((size_t)bh * 128 + nt * 16 + l15) * 2048 + key] = pk;
            }
        }
    }
}

// ---------------------------------------------------------------------------
// outpath: y = lrelu(sum_h enh_h @ Wcomb_h^T + bconst); out = lrelu(y@wf2^T+bf2)
// grid 64 (b*16 + mtile of 64 rows), block 256 (4 waves x 16 rows).
__global__ __launch_bounds__(256) void outpath2(
    const ushort* __restrict__ E, const ushort* __restrict__ Wcomb,
    const float* __restrict__ bconst, const ushort* __restrict__ Wf2bf,
    const float* __restrict__ Bf2, float* __restrict__ OUT)
{
    __shared__ ushort Wc[128 * 128], W2l[128 * 128];
    __shared__ ushort tl[4][16 * 128];
    const int tid = threadIdx.x, lane = tid & 63, w = tid >> 6;
    const int l15 = lane & 15, lk8 = (lane >> 4) * 8, lr4 = (lane >> 4) * 4;
    const int b = blockIdx.x >> 4;
    const int m0 = (blockIdx.x & 15) * 64;
    stage_wbf(Wf2bf, W2l, tid);
    float bc[8], b2[8];
    #pragma unroll
    for (int nt = 0; nt < 8; ++nt) { bc[nt] = bconst[nt * 16 + l15]; b2[nt] = Bf2[nt * 16 + l15]; }

    const f32x4 z = {0.f, 0.f, 0.f, 0.f};
    f32x4 yacc[8];
    #pragma unroll
    for (int i = 0; i < 8; ++i) yacc[i] = z;

    bf16x8 a[4], an[4];
    auto loadE = [&](int h, bf16x8 dst[4]) {
        const size_t er = ((size_t)((b * 8 + h) * 1024) + m0 + w * 16 + l15) * 128;
        #pragma unroll
        for (int ds = 0; ds < 4; ++ds) dst[ds] = *(const bf16x8*)(E + er + ds * 32 + lk8);
    };
    loadE(0, a);
    #pragma unroll
    for (int ds = 0; ds < 4; ++ds) an[ds] = a[ds];

    for (int h = 0; h < 8; ++h) {
        __syncthreads();                 // prior layer8 done reading Wc
        stage_wbf(Wcomb + h * 16384, Wc, tid);
        if (h < 7) loadE(h + 1, an);
        __syncthreads();                 // Wc visible
        layer8swz(a, Wc, yacc, l15, lk8);
        #pragma unroll
        for (int ds = 0; ds < 4; ++ds) a[ds] = an[ds];
    }
    bf16x8 a3[4];
    retile_swz<1>(yacc, bc, tl[w], l15, lr4, lk8, a3);
    f32x4 oacc[8];
    #pragma unroll
    for (int i = 0; i < 8; ++i) oacc[i] = z;
    layer8swz(a3, W2l, oacc, l15, lk8);
    #pragma unroll
    for (int nt = 0; nt < 8; ++nt)
        #pragma unroll
        for (int j = 0; j < 4; ++j)
            OUT[((size_t)b * 1024 + m0 + w * 16 + lr4 + j) * 128 + nt * 16 + l15] =
                act_lrelu(oacc[nt][j] + b2[nt]);
}

// ---------------------------------------------------------------------------
// bf16 MFMA flash attention (unchanged from R3).
__global__ __launch_bounds__(256, 2) void flash_attn_bf16(
    const ushort* __restrict__ Q, const ushort* __restrict__ Kx,
    const ushort* __restrict__ Vt, ushort* __restrict__ O)
{
    constexpr float SCALE = 0.08838834764831845f;
    const int bh = blockIdx.y;
    const int m0 = blockIdx.x * 64;
    const int tid = threadIdx.x;
    const int lane = tid & 63, w = tid >> 6;
    const int l15 = lane & 15, lk8 = (lane >> 4) * 8, lr4 = (lane >> 4) * 4;

    __shared__ ushort K_lds[2][64 * 136];
    __shared__ ushort V_lds[2][128 * 72];
    __shared__ ushort P_lds[64 * 72];

    const ushort* Qb = Q + (size_t)bh * 1024 * 128;
    const ushort* Kb = Kx + (size_t)bh * 2048 * 128;
    const ushort* Vb = Vt + (size_t)bh * 128 * 2048;

    bf16x8 qf[4];
    {
        const int row = m0 + w * 16 + l15;
        #pragma unroll
        for (int ds = 0; ds < 4; ++ds)
            qf[ds] = *(const bf16x8*)(Qb + (size_t)row * 128 + ds * 32 + lk8);
    }

    const int kr = tid >> 4, kc = (tid & 15) * 8;
    const int vr = tid >> 3, vc = (tid & 7) * 8;
    bf16x8 kreg[4], vreg[4];
    #pragma unroll
    for (int it = 0; it < 4; ++it) {
        kreg[it] = *(const bf16x8*)(Kb + (size_t)(kr + it * 16) * 128 + kc);
        vreg[it] = *(const bf16x8*)(Vb + (size_t)(vr + it * 32) * 2048 + vc);
    }
    #pragma unroll
    for (int it = 0; it < 4; ++it) {
        *(bf16x8*)&K_lds[0][(kr + it * 16) * 136 + kc] = kreg[it];
        *(bf16x8*)&V_lds[0][(vr + it * 32) * 72 + vc] = vreg[it];
    }
    __syncthreads();

    f32x4 oacc[8];
    #pragma unroll
    for (int i = 0; i < 8; ++i) oacc[i] = f32x4{0.f, 0.f, 0.f, 0.f};
    float mrun[4] = {-1e30f, -1e30f, -1e30f, -1e30f};
    float lrun[4] = {0.f, 0.f, 0.f, 0.f};
    int cur = 0;

    for (int nt = 0; nt < 32; ++nt) {
        if (nt < 31) {
            const int n1 = (nt + 1) * 64;
            #pragma unroll
            for (int it = 0; it < 4; ++it) {
                kreg[it] = *(const bf16x8*)(Kb + (size_t)(n1 + kr + it * 16) * 128 + kc);
                vreg[it] = *(const bf16x8*)(Vb + (size_t)(vr + it * 32) * 2048 + n1 + vc);
            }
        }
        const ushort* Kc = &K_lds[cur][0];
        const ushort* Vc = &V_lds[cur][0];

        f32x4 s[4];
        #pragma unroll
        for (int i = 0; i < 4; ++i) s[i] = f32x4{0.f, 0.f, 0.f, 0.f};
        __builtin_amdgcn_s_setprio(1);
        #pragma unroll
        for (int ds = 0; ds < 4; ++ds)
            #pragma unroll
            for (int ct = 0; ct < 4; ++ct) {
                const bf16x8 bfr = *(const bf16x8*)&Kc[(ct * 16 + l15) * 136 + ds * 32 + lk8];
                s[ct] = __builtin_amdgcn_mfma_f32_16x16x32_bf16(qf[ds], bfr, s[ct], 0, 0, 0);
            }
        __builtin_amdgcn_s_setprio(0);

        float mx[4], p[4][4], fsc[4];
        #pragma unroll
        for (int j = 0; j < 4; ++j)
            mx[j] = fmaxf(fmaxf(s[0][j], s[1][j]), fmaxf(s[2][j], s[3][j])) * SCALE;
        #pragma unroll
        for (int off = 1; off <= 8; off <<= 1)
            #pragma unroll
            for (int j = 0; j < 4; ++j)
                mx[j] = fmaxf(mx[j], __shfl_xor(mx[j], off));
        #pragma unroll
        for (int j = 0; j < 4; ++j) {
            const float mnew = fmaxf(mrun[j], mx[j]);
            fsc[j] = __expf(mrun[j] - mnew);
            mrun[j] = mnew;
            float sum = 0.f;
            #pragma unroll
            for (int ct = 0; ct < 4; ++ct) {
                const float e = __expf(s[ct][j] * SCALE - mnew);
                p[ct][j] = e;
                sum += e;
            }
            sum += __shfl_xor(sum, 1); sum += __shfl_xor(sum, 2);
            sum += __shfl_xor(sum, 4); sum += __shfl_xor(sum, 8);
            lrun[j] = lrun[j] * fsc[j] + sum;
        }
        #pragma unroll
        for (int j = 0; j < 4; ++j) {
            const int prow = w * 16 + lr4 + j;
            #pragma unroll
            for (int ct = 0; ct < 4; ++ct)
                P_lds[prow * 72 + ct * 16 + l15] = f2bf(p[ct][j]);
        }
        #pragma unroll
        for (int dt = 0; dt < 8; ++dt)
            #pragma unroll
            for (int j = 0; j < 4; ++j)
                oacc[dt][j] *= fsc[j];

        __builtin_amdgcn_s_setprio(1);
        #pragma unroll
        for (int ks = 0; ks < 2; ++ks) {
            const bf16x8 pa = *(const bf16x8*)&P_lds[(w * 16 + l15) * 72 + ks * 32 + lk8];
            #pragma unroll
            for (int dt = 0; dt < 8; ++dt) {
                const bf16x8 vb = *(const bf16x8*)&Vc[(dt * 16 + l15) * 72 + ks * 32 + lk8];
                oacc[dt] = __builtin_amdgcn_mfma_f32_16x16x32_bf16(pa, vb, oacc[dt], 0, 0, 0);
            }
        }
        __builtin_amdgcn_s_setprio(0);

        if (nt < 31) {
            const int nxt = cur ^ 1;
            #pragma unroll
            for (int it = 0; it < 4; ++it) {
                *(bf16x8*)&K_lds[nxt][(kr + it * 16) * 136 + kc] = kreg[it];
                *(bf16x8*)&V_lds[nxt][(vr + it * 32) * 72 + vc] = vreg[it];
            }
        }
        __syncthreads();
        cur ^= 1;
    }

    ushort* Ob = O + (size_t)bh * 1024 * 128;
    #pragma unroll
    for (int j = 0; j < 4; ++j) {
        const float inv = 1.0f / lrun[j];
        const int row = m0 + w * 16 + lr4 + j;
        #pragma unroll
        for (int dt = 0; dt < 8; ++dt)
            Ob[(size_t)row * 128 + dt * 16 + l15] = f2bf(oacc[dt][j] * inv);
    }
}

// ---------------------------------------------------------------------------
extern "C" void kernel_launch(void* const* d_in, const int* in_sizes, int n_in,
                              void* d_out, int out_size, void* d_ws, size_t ws_size,
                              hipStream_t stream)
{
    (void)in_sizes; (void)n_in; (void)out_size; (void)ws_size;
    const float* query = (const float*)d_in[0];
    const float* fts   = (const float*)d_in[1];
    const float* wqc = (const float*)d_in[2];
    const float* bqc = (const float*)d_in[3];
    const float* wq1 = (const float*)d_in[4];
    const float* bq1 = (const float*)d_in[5];
    const float* wq2 = (const float*)d_in[6];
    const float* bq2 = (const float*)d_in[7];
    const float* wk1 = (const float*)d_in[8];
    const float* bk1 = (const float*)d_in[9];
    const float* wk2 = (const float*)d_in[10];
    const float* bk2 = (const float*)d_in[11];
    const float* wv1 = (const float*)d_in[12];
    const float* bv1 = (const float*)d_in[13];
    const float* wv2 = (const float*)d_in[14];
    const float* bv2 = (const float*)d_in[15];
    const float* wo  = (const float*)d_in[16];
    const float* bo  = (const float*)d_in[17];
    const float* wf1 = (const float*)d_in[18];
    const float* bf1 = (const float*)d_in[19];
    const float* wf2 = (const float*)d_in[20];
    const float* bf2 = (const float*)d_in[21];
    float* out = (float*)d_out;

    // ws layout (~77.3 MB)
    char* ws = (char*)d_ws;
    ushort* ftb    = (ushort*)(ws + 0LL);          // 16 MB [32][2048][128]
    ushort* queryT = (ushort*)(ws + 16777216LL);   //  1 MB [4][1024][128]
    ushort* qh     = (ushort*)(ws + 17825792LL);   //  8 MB [32][1024][128]
    ushort* qbuf   = (ushort*)(ws + 26214400LL);   //  8 MB [32][1024][128]
    ushort* kbuf   = (ushort*)(ws + 34603008LL);   // 16 MB [32][2048][128]
    ushort* vbufT  = (ushort*)(ws + 51380224LL);   // 16 MB [32][128][2048]
    ushort* enh    = (ushort*)(ws + 68157440LL);   //  8 MB [32][1024][128]
    ushort* Wbf    = (ushort*)(ws + 76546048LL);   // 480 KB converted weights
    ushort* Wcomb  = (ushort*)(ws + 77037568LL);   // 256 KB [8][128][128]
    float*  bconst = (float*) (ws + 77299712LL);   // 512 B

    // bf16 weight sub-offsets (ushort units)
    ushort* wqc_b = Wbf + 0;
    ushort* wq1_b = Wbf + 131072;
    ushort* wq2_b = Wbf + 147456;
    ushort* wk1_b = Wbf + 163840;
    ushort* wk2_b = Wbf + 180224;
    ushort* wv1_b = Wbf + 196608;
    ushort* wv2_b = Wbf + 212992;
    ushort* wf2_b = Wbf + 229376;

    prep_kernel<<<69, 256, 0, stream>>>(wqc, wq1, wq2, wk1, wk2, wv1, wv2, wf2,
                                        wf1, wo, bo, bf1, Wbf, Wcomb, bconst);
    transpose_cast<<<dim3(32, 2, 32), 256, 0, stream>>>(fts, ftb, 128, 2048);
    transpose_cast<<<dim3(16, 2, 4), 256, 0, stream>>>(query, queryT, 128, 1024);
    // q-path: qconv (per-head) then shared 2-layer MLP
    mlp1v<true><<<256, 256, 0, stream>>>(queryT, wqc_b, bqc, qh);
    mlp2v<1, 2, false><<<256, 256, 0, stream>>>(qh, wq1_b, bq1, wq2_b, bq2, qbuf);
    // k-path / v-path
    mlp2v<1, 2, false><<<512, 256, 0, stream>>>(ftb, wk1_b, bk1, wk2_b, bk2, kbuf);
    mlp2v<1, 2, true><<<512, 256, 0, stream>>>(ftb, wv1_b, bv1, wv2_b, bv2, vbufT);
    // attention
    flash_attn_bf16<<<dim3(16, 32), 256, 0, stream>>>(qbuf, kbuf, vbufT, enh);
    // fused proj_out+concat+final MLP (Wcomb-folded)
    outpath2<<<64, 256, 0, stream>>>(enh, Wcomb, bconst, wf2_b, bf2, out);
}